// Round 6
// baseline (41228.400 us; speedup 1.0000x reference)
//
#include <hip/hip_runtime.h>
#include <hip/hip_bf16.h>

#define NB 32
#define NBLK 64
#define TT 512
#define DD 20

using bf16x8 = __attribute__((ext_vector_type(8))) short;
using f32x4  = __attribute__((ext_vector_type(4))) float;

// workspace byte offsets (prep output)
#define OFF_WIH0  0          // 1024x20  -> 64 tiles x 1 kt (stride 1024)
#define OFF_WHH0  65536      // 1024x256 -> 64 tiles x 8 kt (stride 8192)
#define OFF_WIH1  589824
#define OFF_WHH1  1114112
#define OFF_WPROJ 1638400    // 20x256 -> 2 tiles x 8 kt
#define OFF_B0    1654784
#define OFF_B1    1658880

// smem layout (bytes) — no weight staging: weights go global->VGPR directly
#define SM_H0    0        // 32*264*2 = 16896 (in-place, [m*264 + u])
#define SM_H1    16896    // 16896
#define SM_XB    33792    // 32*32*2 = 2048
#define SM_WPS   35840    // 16384 (W_proj resident)
#define SM_ZB    52224    // 4096
#define SM_CI    56320    // 65536 (c-init scratch)
#define SM_TOTAL 121856

__device__ __forceinline__ float sigf(float x) { return 1.0f / (1.0f + __expf(-x)); }
__device__ __forceinline__ float tanhfast(float x) { return 1.0f - 2.0f / (__expf(2.0f * x) + 1.0f); }

// ---- asm weight-fragment load: global->VGPR, opaque to the compiler's waitcnt pass ----
__device__ __forceinline__ void gload16(bf16x8& dst, const void* addr) {
    asm volatile("global_load_dwordx4 %0, %1, off" : "=v"(dst) : "v"(addr));
}
// wait until <=N vmem ops outstanding; re-defines the batch so every consumer depends on it
__device__ __forceinline__ void wait_batch(int n, bf16x8 (&f)[8]) {
    if (n >= 16)
        asm volatile("s_waitcnt vmcnt(16)"
                     : "+v"(f[0]), "+v"(f[1]), "+v"(f[2]), "+v"(f[3]),
                       "+v"(f[4]), "+v"(f[5]), "+v"(f[6]), "+v"(f[7]) :: "memory");
    else if (n >= 8)
        asm volatile("s_waitcnt vmcnt(8)"
                     : "+v"(f[0]), "+v"(f[1]), "+v"(f[2]), "+v"(f[3]),
                       "+v"(f[4]), "+v"(f[5]), "+v"(f[6]), "+v"(f[7]) :: "memory");
    else
        asm volatile("s_waitcnt vmcnt(0)"
                     : "+v"(f[0]), "+v"(f[1]), "+v"(f[2]), "+v"(f[3]),
                       "+v"(f[4]), "+v"(f[5]), "+v"(f[6]), "+v"(f[7]) :: "memory");
}

// ---- prep: fp32 weights -> bf16, swizzled into MFMA B-fragment order ----
__global__ void prep_kernel(const float* __restrict__ wih0, const float* __restrict__ whh0,
                            const float* __restrict__ wih1, const float* __restrict__ whh1,
                            const float* __restrict__ wproj,
                            const float* __restrict__ bih0, const float* __restrict__ bhh0,
                            const float* __restrict__ bih1, const float* __restrict__ bhh1,
                            char* __restrict__ ws) {
    int idx = blockIdx.x * 256 + threadIdx.x;
    const float* src;
    __hip_bfloat16* dst;
    int e, N, K, nKt;
    if (idx < 32768)       { e = idx;          src = wih0;  N = 1024; K = 20;  nKt = 1; dst = (__hip_bfloat16*)(ws + OFF_WIH0); }
    else if (idx < 294912) { e = idx - 32768;  src = whh0;  N = 1024; K = 256; nKt = 8; dst = (__hip_bfloat16*)(ws + OFF_WHH0); }
    else if (idx < 557056) { e = idx - 294912; src = wih1;  N = 1024; K = 256; nKt = 8; dst = (__hip_bfloat16*)(ws + OFF_WIH1); }
    else if (idx < 819200) { e = idx - 557056; src = whh1;  N = 1024; K = 256; nKt = 8; dst = (__hip_bfloat16*)(ws + OFF_WHH1); }
    else if (idx < 827392) { e = idx - 819200; src = wproj; N = 20;   K = 256; nKt = 8; dst = (__hip_bfloat16*)(ws + OFF_WPROJ); }
    else if (idx < 828416) { int j = idx - 827392; ((float*)(ws + OFF_B0))[j] = bih0[j] + bhh0[j]; return; }
    else if (idx < 829440) { int j = idx - 828416; ((float*)(ws + OFF_B1))[j] = bih1[j] + bhh1[j]; return; }
    else return;
    int j    = e & 7;
    int lane = (e >> 3) & 63;
    int tile = e >> 9;
    int kt = tile % nKt;
    int nt = tile / nKt;
    int n = nt * 16 + (lane & 15);
    int k = kt * 32 + ((lane >> 4) << 3) + j;
    float v = (n < N && k < K) ? src[n * K + k] : 0.0f;
    dst[e] = __float2bfloat16(v);
}

// ---- persistent decoder: 64 blocks x 512 threads, 32 batch rows/block, 512 steps ----
__global__ __launch_bounds__(512, 1) void decoder_kernel(
    const float* __restrict__ z, const float* __restrict__ w_lh, const float* __restrict__ b_lh,
    const float* __restrict__ w_lc, const float* __restrict__ b_lc,
    const float* __restrict__ b_proj, const char* __restrict__ ws,
    float* __restrict__ out) {

    __shared__ __align__(16) char smem[SM_TOTAL];

    const int tid = threadIdx.x;
    const int b0  = blockIdx.x * NB;

    __hip_bfloat16* h0p = (__hip_bfloat16*)(smem + SM_H0);
    __hip_bfloat16* h1p = (__hip_bfloat16*)(smem + SM_H1);
    __hip_bfloat16* xbh = (__hip_bfloat16*)(smem + SM_XB);

    // ---- init: stage z, zero xb, stage W_proj ----
    {
        float* zbf = (float*)(smem + SM_ZB);
        zbf[tid]       = z[(b0 + (tid >> 5)) * 32 + (tid & 31)];
        int i2 = tid + 512;
        zbf[i2]        = z[(b0 + (i2 >> 5)) * 32 + (i2 & 31)];
        ((unsigned int*)(smem + SM_XB))[tid] = 0;
        const bf16x8* sp = (const bf16x8*)(ws + OFF_WPROJ);
        bf16x8* dp = (bf16x8*)(smem + SM_WPS);
        dp[tid] = sp[tid];
        dp[tid + 512] = sp[tid + 512];
    }
    __syncthreads();

    // ---- h/c init (fp32 VALU, K=32): 32 rows x 512 cols ----
    {
        float* cinitf = (float*)(smem + SM_CI);
        const float* zbf = (const float*)(smem + SM_ZB);
        for (int ii = 0; ii < 32; ii++) {
            int pi = ii * 512 + tid;
            int b = pi >> 9, col = pi & 511;
            float dh = b_lh[col], dc = b_lc[col];
            #pragma unroll 8
            for (int k = 0; k < 32; k++) {
                float zv = zbf[b * 32 + k];
                dh += zv * w_lh[col * 32 + k];
                dc += zv * w_lc[col * 32 + k];
            }
            if (col < 256) { h0p[b * 264 + col]         = __float2bfloat16(dh); cinitf[b * 256 + col]                 = dc; }
            else           { h1p[b * 264 + (col - 256)] = __float2bfloat16(dh); cinitf[8192 + b * 256 + (col - 256)] = dc; }
        }
    }
    __syncthreads();

    const int wv = tid >> 6, ln = tid & 63;
    const int l15 = ln & 15, lq = ln >> 4;
    const int lnoff = ln * 16;

    float c0r[2][2][4], c1r[2][2][4];
    {
        const float* cinitf = (const float*)(smem + SM_CI);
        #pragma unroll
        for (int mt = 0; mt < 2; mt++)
            #pragma unroll
            for (int h = 0; h < 2; h++)
                #pragma unroll
                for (int r = 0; r < 4; r++) {
                    int m = mt * 16 + lq * 4 + r, u = wv * 32 + h * 16 + l15;
                    c0r[mt][h][r] = cinitf[m * 256 + u];
                    c1r[mt][h][r] = cinitf[8192 + m * 256 + u];
                }
    }

    const float* bias0 = (const float*)(ws + OFF_B0);
    const float* bias1 = (const float*)(ws + OFF_B1);
    float bs0[8], bs1[8];
    #pragma unroll
    for (int q = 0; q < 8; q++) {
        int col = (q >> 1) * 256 + wv * 32 + (q & 1) * 16 + l15;
        bs0[q] = bias0[col];
        bs1[q] = bias1[col];
    }
    const int pc_nt = wv & 1, pc_mt = wv >> 1;
    const int pc_col = pc_nt * 16 + l15;
    const float bpj = (wv < 4 && pc_col < 20) ? b_proj[pc_col] : 0.0f;

    int bo8[8], bo1[8];
    #pragma unroll
    for (int q = 0; q < 8; q++) {
        int tbq = (q >> 1) * 16 + wv * 2 + (q & 1);
        bo8[q] = tbq * 8192 + lnoff;
        bo1[q] = tbq * 1024 + lnoff;
    }

    const char* W0x = ws + OFF_WIH0;
    const char* W0h = ws + OFF_WHH0;
    const char* W1x = ws + OFF_WIH1;
    const char* W1h = ws + OFF_WHH1;
    const char* wps_c = smem + SM_WPS;
    const char* h0c = smem + SM_H0;
    const char* h1c = smem + SM_H1;
    const char* xbc = smem + SM_XB;

    float* outp = out;

    // phase C (waves 0..3): y(t-1) -> out, x(t) -> xb. Reads h1 (state of t-1). Pure LDS + stores.
    auto phaseC = [&](int t) {
        f32x4 py = {bpj, bpj, bpj, bpj};
        #pragma unroll
        for (int kt = 0; kt < 8; kt++) {
            bf16x8 ah = *(const bf16x8*)(h1c + (pc_mt * 16 + l15) * 528 + kt * 64 + lq * 16);
            bf16x8 wf = *(const bf16x8*)(wps_c + pc_nt * 8192 + kt * 1024 + lnoff);
            py = __builtin_amdgcn_mfma_f32_16x16x32_bf16(ah, wf, py, 0, 0, 0);
        }
        if (pc_col < 20) {
            #pragma unroll
            for (int r = 0; r < 4; r++) {
                int row = pc_mt * 16 + lq * 4 + r;
                outp[((size_t)(b0 + row) * TT + (t - 1)) * DD + pc_col] = py[r];
                xbh[row * 32 + pc_col] = __float2bfloat16(py[r]);
            }
        }
    };

    f32x4 acc[8][2];
    bf16x8 wf[3][8];

    #pragma unroll 1
    for (int t = 0; t < TT; t++) {
        // phase C(t-1) on waves 0-3; other waves run ahead into phase A (sync at kt8 barrier)
        if (t > 0 && wv < 4) phaseC(t);

        // ======== phase A: gates0 = bias0 + h0 @ W0h^T + x @ W0x^T ========
        #pragma unroll
        for (int q = 0; q < 8; q++) {
            f32x4 v = {bs0[q], bs0[q], bs0[q], bs0[q]};
            acc[q][0] = v; acc[q][1] = v;
        }
        // prologue: batches 0,1 (W0h kt0, kt1)
        #pragma unroll
        for (int b = 0; b < 2; b++)
            #pragma unroll
            for (int q = 0; q < 8; q++)
                gload16(wf[b][q], W0h + bo8[q] + b * 1024);

        #pragma unroll
        for (int kt = 0; kt < 8; kt++) {
            if (kt + 2 < 8) {
                #pragma unroll
                for (int q = 0; q < 8; q++)
                    gload16(wf[(kt + 2) % 3][q], W0h + bo8[q] + (kt + 2) * 1024);
            } else if (kt + 2 == 8) {
                #pragma unroll
                for (int q = 0; q < 8; q++)
                    gload16(wf[2][q], W0x + bo1[q]);   // batch 8 = W0x (8%3==2)
            }
            wait_batch(kt <= 6 ? 16 : 8, wf[kt % 3]);
            bf16x8 af0 = *(const bf16x8*)(h0c + l15 * 528 + kt * 64 + lq * 16);
            bf16x8 af1 = *(const bf16x8*)(h0c + (16 + l15) * 528 + kt * 64 + lq * 16);
            #pragma unroll
            for (int q = 0; q < 8; q++) {
                acc[q][0] = __builtin_amdgcn_mfma_f32_16x16x32_bf16(af0, wf[kt % 3][q], acc[q][0], 0, 0, 0);
                acc[q][1] = __builtin_amdgcn_mfma_f32_16x16x32_bf16(af1, wf[kt % 3][q], acc[q][1], 0, 0, 0);
            }
        }
        // batch 8: W0x with A = x(t); barrier = xb ready + all h0_old reads complete
        wait_batch(0, wf[2]);
        __syncthreads();
        {
            bf16x8 ax0 = *(const bf16x8*)(xbc + l15 * 64 + lq * 16);
            bf16x8 ax1 = *(const bf16x8*)(xbc + (16 + l15) * 64 + lq * 16);
            #pragma unroll
            for (int q = 0; q < 8; q++) {
                acc[q][0] = __builtin_amdgcn_mfma_f32_16x16x32_bf16(ax0, wf[2][q], acc[q][0], 0, 0, 0);
                acc[q][1] = __builtin_amdgcn_mfma_f32_16x16x32_bf16(ax1, wf[2][q], acc[q][1], 0, 0, 0);
            }
        }
        // ---- EW-A: c0,h0 update (in place; h0 reads all completed before barrier above) ----
        #pragma unroll
        for (int mt = 0; mt < 2; mt++)
            #pragma unroll
            for (int h = 0; h < 2; h++)
                #pragma unroll
                for (int r = 0; r < 4; r++) {
                    float iv = acc[0 + h][mt][r], fv = acc[2 + h][mt][r];
                    float gv = acc[4 + h][mt][r], ov = acc[6 + h][mt][r];
                    float cn = sigf(fv) * c0r[mt][h][r] + sigf(iv) * tanhfast(gv);
                    float hn = sigf(ov) * tanhfast(cn);
                    c0r[mt][h][r] = cn;
                    h0p[(mt * 16 + lq * 4 + r) * 264 + wv * 32 + h * 16 + l15] = __float2bfloat16(hn);
                }
        __syncthreads(); // h0_new visible

        // ======== phase B: gates1 = bias1 + h0_new @ W1x^T + h1 @ W1h^T ========
        #pragma unroll
        for (int q = 0; q < 8; q++) {
            f32x4 v = {bs1[q], bs1[q], bs1[q], bs1[q]};
            acc[q][0] = v; acc[q][1] = v;
        }
        #pragma unroll
        for (int b = 0; b < 2; b++)
            #pragma unroll
            for (int q = 0; q < 8; q++)
                gload16(wf[b][q], W1x + bo8[q] + b * 1024);

        #pragma unroll
        for (int s = 0; s < 16; s++) {
            const int ns = s + 2;
            if (ns < 16) {
                const char* wb = (ns < 8) ? (W1x + ns * 1024) : (W1h + (ns - 8) * 1024);
                #pragma unroll
                for (int q = 0; q < 8; q++)
                    gload16(wf[ns % 3][q], wb + bo8[q]);
            }
            wait_batch(s <= 13 ? 16 : (s == 14 ? 8 : 0), wf[s % 3]);
            const char* ab = (s < 8) ? h0c : h1c;
            const int kt = s & 7;
            bf16x8 af0 = *(const bf16x8*)(ab + l15 * 528 + kt * 64 + lq * 16);
            bf16x8 af1 = *(const bf16x8*)(ab + (16 + l15) * 528 + kt * 64 + lq * 16);
            #pragma unroll
            for (int q = 0; q < 8; q++) {
                acc[q][0] = __builtin_amdgcn_mfma_f32_16x16x32_bf16(af0, wf[s % 3][q], acc[q][0], 0, 0, 0);
                acc[q][1] = __builtin_amdgcn_mfma_f32_16x16x32_bf16(af1, wf[s % 3][q], acc[q][1], 0, 0, 0);
            }
        }
        __syncthreads(); // all h1_old / h0_new reads complete block-wide

        // ---- EW-B: c1,h1 update (in place) ----
        #pragma unroll
        for (int mt = 0; mt < 2; mt++)
            #pragma unroll
            for (int h = 0; h < 2; h++)
                #pragma unroll
                for (int r = 0; r < 4; r++) {
                    float iv = acc[0 + h][mt][r], fv = acc[2 + h][mt][r];
                    float gv = acc[4 + h][mt][r], ov = acc[6 + h][mt][r];
                    float cn = sigf(fv) * c1r[mt][h][r] + sigf(iv) * tanhfast(gv);
                    float hn = sigf(ov) * tanhfast(cn);
                    c1r[mt][h][r] = cn;
                    h1p[(mt * 16 + lq * 4 + r) * 264 + wv * 32 + h * 16 + l15] = __float2bfloat16(hn);
                }
        __syncthreads(); // h1_new visible (next step's phaseC + phase B read it)
    }

    // final y(TT-1)
    if (wv < 4) phaseC(TT);
}

extern "C" void kernel_launch(void* const* d_in, const int* in_sizes, int n_in,
                              void* d_out, int out_size, void* d_ws, size_t ws_size,
                              hipStream_t stream) {
    const float* z      = (const float*)d_in[0];
    const float* w_lh   = (const float*)d_in[3];
    const float* b_lh   = (const float*)d_in[4];
    const float* w_lc   = (const float*)d_in[5];
    const float* b_lc   = (const float*)d_in[6];
    const float* w_ih0  = (const float*)d_in[7];
    const float* w_hh0  = (const float*)d_in[8];
    const float* b_ih0  = (const float*)d_in[9];
    const float* b_hh0  = (const float*)d_in[10];
    const float* w_ih1  = (const float*)d_in[11];
    const float* w_hh1  = (const float*)d_in[12];
    const float* b_ih1  = (const float*)d_in[13];
    const float* b_hh1  = (const float*)d_in[14];
    const float* w_proj = (const float*)d_in[15];
    const float* b_proj = (const float*)d_in[16];
    char* ws = (char*)d_ws;
    float* out = (float*)d_out;

    prep_kernel<<<3240, 256, 0, stream>>>(w_ih0, w_hh0, w_ih1, w_hh1, w_proj,
                                          b_ih0, b_hh0, b_ih1, b_hh1, ws);
    decoder_kernel<<<NBLK, 512, 0, stream>>>(z, w_lh, b_lh, w_lc, b_lc, b_proj, ws, out);
}

// Round 7
// 38339.612 us; speedup vs baseline: 1.0753x; 1.0753x over previous
//
#include <hip/hip_runtime.h>
#include <hip/hip_bf16.h>

#define NB 32
#define NBLK 64
#define TT 512
#define DD 20

using bf16x8 = __attribute__((ext_vector_type(8))) short;
using f32x4  = __attribute__((ext_vector_type(4))) float;

typedef __attribute__((address_space(3))) unsigned int lds_uint;
typedef __attribute__((address_space(1))) unsigned int glob_uint;

// workspace byte offsets (prep output)
#define OFF_WIH0  0          // 1024x20  -> 64 tiles (stride 1024)
#define OFF_WHH0  65536      // 1024x256 -> 64 tiles x 8 kt (stride 8192)
#define OFF_WIH1  589824
#define OFF_WHH1  1114112
#define OFF_WPROJ 1638400    // 20x256 -> 2 tiles x 8 kt
#define OFF_B0    1654784
#define OFF_B1    1658880

// smem layout (bytes)
#define SM_PAN   0        // 3 panels x 32768 = 98304 (CI 64K + ZB 4K overlay during init)
#define SM_H0    98304    // 32*264*2 = 16896 (in-place)
#define SM_H1    115200   // 16896
#define SM_XB    132096   // 2048
#define SM_WPS   134144   // 16384 (W_proj resident)
#define SM_TOTAL 150528
#define SM_CI    0        // init overlay
#define SM_ZB    65536    // init overlay

__device__ __forceinline__ float sigf(float x) { return 1.0f / (1.0f + __expf(-x)); }
__device__ __forceinline__ float tanhfast(float x) { return 1.0f - 2.0f / (__expf(2.0f * x) + 1.0f); }

__device__ __forceinline__ void stage16(const char* g, const char* l) {
    __builtin_amdgcn_global_load_lds((glob_uint*)g, (lds_uint*)l, 16, 0, 0);
}
// own-deposit pacing: at most 4 vmem ops outstanding (the newest panel)
__device__ __forceinline__ void wait_vm4() { asm volatile("s_waitcnt vmcnt(4)" ::: "memory"); }
// execution barrier + LDS drain, WITHOUT the compiler's vmcnt(0) drain
__device__ __forceinline__ void barrier_nd() { asm volatile("s_waitcnt lgkmcnt(0)\ns_barrier" ::: "memory"); }

// ---- prep: fp32 weights -> bf16, swizzled into MFMA B-fragment order ----
__global__ void prep_kernel(const float* __restrict__ wih0, const float* __restrict__ whh0,
                            const float* __restrict__ wih1, const float* __restrict__ whh1,
                            const float* __restrict__ wproj,
                            const float* __restrict__ bih0, const float* __restrict__ bhh0,
                            const float* __restrict__ bih1, const float* __restrict__ bhh1,
                            char* __restrict__ ws) {
    int idx = blockIdx.x * 256 + threadIdx.x;
    const float* src;
    __hip_bfloat16* dst;
    int e, N, K, nKt;
    if (idx < 32768)       { e = idx;          src = wih0;  N = 1024; K = 20;  nKt = 1; dst = (__hip_bfloat16*)(ws + OFF_WIH0); }
    else if (idx < 294912) { e = idx - 32768;  src = whh0;  N = 1024; K = 256; nKt = 8; dst = (__hip_bfloat16*)(ws + OFF_WHH0); }
    else if (idx < 557056) { e = idx - 294912; src = wih1;  N = 1024; K = 256; nKt = 8; dst = (__hip_bfloat16*)(ws + OFF_WIH1); }
    else if (idx < 819200) { e = idx - 557056; src = whh1;  N = 1024; K = 256; nKt = 8; dst = (__hip_bfloat16*)(ws + OFF_WHH1); }
    else if (idx < 827392) { e = idx - 819200; src = wproj; N = 20;   K = 256; nKt = 8; dst = (__hip_bfloat16*)(ws + OFF_WPROJ); }
    else if (idx < 828416) { int j = idx - 827392; ((float*)(ws + OFF_B0))[j] = bih0[j] + bhh0[j]; return; }
    else if (idx < 829440) { int j = idx - 828416; ((float*)(ws + OFF_B1))[j] = bih1[j] + bhh1[j]; return; }
    else return;
    int j    = e & 7;
    int lane = (e >> 3) & 63;
    int tile = e >> 9;
    int kt = tile % nKt;
    int nt = tile / nKt;
    int n = nt * 16 + (lane & 15);
    int k = kt * 32 + ((lane >> 4) << 3) + j;
    float v = (n < N && k < K) ? src[n * K + k] : 0.0f;
    dst[e] = __float2bfloat16(v);
}

// ---- persistent decoder: 64 blocks x 512 threads, 32 batch rows/block, 512 steps ----
__global__ __launch_bounds__(512, 1) void decoder_kernel(
    const float* __restrict__ z, const float* __restrict__ w_lh, const float* __restrict__ b_lh,
    const float* __restrict__ w_lc, const float* __restrict__ b_lc,
    const float* __restrict__ b_proj, const char* __restrict__ ws,
    float* __restrict__ out) {

    __shared__ __align__(16) char smem[SM_TOTAL];

    const int tid = threadIdx.x;
    const int b0  = blockIdx.x * NB;

    __hip_bfloat16* h0p = (__hip_bfloat16*)(smem + SM_H0);
    __hip_bfloat16* h1p = (__hip_bfloat16*)(smem + SM_H1);
    __hip_bfloat16* xbh = (__hip_bfloat16*)(smem + SM_XB);

    // ---- init: stage z, zero xb, stage W_proj ----
    {
        float* zbf = (float*)(smem + SM_ZB);
        zbf[tid]       = z[(b0 + (tid >> 5)) * 32 + (tid & 31)];
        int i2 = tid + 512;
        zbf[i2]        = z[(b0 + (i2 >> 5)) * 32 + (i2 & 31)];
        ((unsigned int*)(smem + SM_XB))[tid] = 0;
        const bf16x8* sp = (const bf16x8*)(ws + OFF_WPROJ);
        bf16x8* dp = (bf16x8*)(smem + SM_WPS);
        dp[tid] = sp[tid];
        dp[tid + 512] = sp[tid + 512];
    }
    __syncthreads();

    // ---- h/c init (fp32 VALU, K=32): 32 rows x 512 cols ----
    {
        float* cinitf = (float*)(smem + SM_CI);
        const float* zbf = (const float*)(smem + SM_ZB);
        for (int ii = 0; ii < 32; ii++) {
            int pi = ii * 512 + tid;
            int b = pi >> 9, col = pi & 511;
            float dh = b_lh[col], dc = b_lc[col];
            #pragma unroll 8
            for (int k = 0; k < 32; k++) {
                float zv = zbf[b * 32 + k];
                dh += zv * w_lh[col * 32 + k];
                dc += zv * w_lc[col * 32 + k];
            }
            if (col < 256) { h0p[b * 264 + col]         = __float2bfloat16(dh); cinitf[b * 256 + col]                 = dc; }
            else           { h1p[b * 264 + (col - 256)] = __float2bfloat16(dh); cinitf[8192 + b * 256 + (col - 256)] = dc; }
        }
    }
    __syncthreads();

    const int wv = tid >> 6, ln = tid & 63;
    const int l15 = ln & 15, lq = ln >> 4;
    const int lnoff = ln * 16;

    float c0r[2][2][4], c1r[2][2][4];
    {
        const float* cinitf = (const float*)(smem + SM_CI);
        #pragma unroll
        for (int mt = 0; mt < 2; mt++)
            #pragma unroll
            for (int h = 0; h < 2; h++)
                #pragma unroll
                for (int r = 0; r < 4; r++) {
                    int m = mt * 16 + lq * 4 + r, u = wv * 32 + h * 16 + l15;
                    c0r[mt][h][r] = cinitf[m * 256 + u];
                    c1r[mt][h][r] = cinitf[8192 + m * 256 + u];
                }
    }
    __syncthreads(); // cinit/zb overlays dead; panel area may be written from here on

    const float* bias0 = (const float*)(ws + OFF_B0);
    const float* bias1 = (const float*)(ws + OFF_B1);
    float bs0[8], bs1[8];
    #pragma unroll
    for (int q = 0; q < 8; q++) {
        int col = (q >> 1) * 256 + wv * 32 + (q & 1) * 16 + l15;
        bs0[q] = bias0[col];
        bs1[q] = bias1[col];
    }
    const int pc_nt = wv & 1, pc_mt = wv >> 1;
    const int pc_col = pc_nt * 16 + l15;
    const float bpj = (wv < 4 && pc_col < 20) ? b_proj[pc_col] : 0.0f;

    const char* W0x = ws + OFF_WIH0;
    const char* W0h = ws + OFF_WHH0;
    const char* W1x = ws + OFF_WIH1;
    const char* W1h = ws + OFF_WHH1;
    const char* wps_c = smem + SM_WPS;
    const char* h0c = smem + SM_H0;
    const char* h1c = smem + SM_H1;
    const char* xbc = smem + SM_XB;

    float* outp = out;

    // stage panel idx (0..49, wraps >=50) into buffer buf. Each wave stages its 4 tiles (4 KB).
    auto stagePanelIdx = [&](int idx, int buf) {
        if (idx >= 50) idx -= 50;
        const char* Wb; int stride, kt, half;
        if (idx < 16)      { Wb = W0h; stride = 8192; kt = idx >> 1;        half = idx & 1; }
        else if (idx < 18) { Wb = W0x; stride = 1024; kt = 0;               half = idx - 16; }
        else if (idx < 34) { Wb = W1x; stride = 8192; kt = (idx - 18) >> 1; half = (idx - 18) & 1; }
        else               { Wb = W1h; stride = 8192; kt = (idx - 34) >> 1; half = (idx - 34) & 1; }
        const char* gsrc = Wb + (half * 32 + wv * 4) * stride + kt * 1024 + lnoff;
        char* ldst = smem + SM_PAN + buf * 32768 + (wv * 4) * 1024;
        #pragma unroll
        for (int j = 0; j < 4; j++)
            stage16(gsrc + j * stride, ldst + j * 1024);
    };

    f32x4 acc[8][2];

    // consume one panel: half selects acc column-block; A from h-state (kt) or xb
    auto consumeH = [&](int buf, int kt, int half, const char* hsrc) {
        const char* pb = smem + SM_PAN + buf * 32768;
        bf16x8 af0 = *(const bf16x8*)(hsrc + l15 * 528 + kt * 64 + lq * 16);
        bf16x8 af1 = *(const bf16x8*)(hsrc + (16 + l15) * 528 + kt * 64 + lq * 16);
        #pragma unroll
        for (int qq = 0; qq < 4; qq++) {
            int lt = (qq >> 1) * 16 + wv * 2 + (qq & 1);
            bf16x8 w = *(const bf16x8*)(pb + lt * 1024 + lnoff);
            acc[half * 4 + qq][0] = __builtin_amdgcn_mfma_f32_16x16x32_bf16(af0, w, acc[half * 4 + qq][0], 0, 0, 0);
            acc[half * 4 + qq][1] = __builtin_amdgcn_mfma_f32_16x16x32_bf16(af1, w, acc[half * 4 + qq][1], 0, 0, 0);
        }
    };
    auto consumeX = [&](int buf, int half) {
        const char* pb = smem + SM_PAN + buf * 32768;
        bf16x8 af0 = *(const bf16x8*)(xbc + l15 * 64 + lq * 16);
        bf16x8 af1 = *(const bf16x8*)(xbc + (16 + l15) * 64 + lq * 16);
        #pragma unroll
        for (int qq = 0; qq < 4; qq++) {
            int lt = (qq >> 1) * 16 + wv * 2 + (qq & 1);
            bf16x8 w = *(const bf16x8*)(pb + lt * 1024 + lnoff);
            acc[half * 4 + qq][0] = __builtin_amdgcn_mfma_f32_16x16x32_bf16(af0, w, acc[half * 4 + qq][0], 0, 0, 0);
            acc[half * 4 + qq][1] = __builtin_amdgcn_mfma_f32_16x16x32_bf16(af1, w, acc[half * 4 + qq][1], 0, 0, 0);
        }
    };

    // phase C (waves 0..3): y(t-1) -> out, x(t) -> xb. Reads h1(t-1). LDS + global stores.
    auto phaseC = [&](int t) {
        f32x4 py = {bpj, bpj, bpj, bpj};
        #pragma unroll
        for (int kt = 0; kt < 8; kt++) {
            bf16x8 ah = *(const bf16x8*)(h1c + (pc_mt * 16 + l15) * 528 + kt * 64 + lq * 16);
            bf16x8 wfr = *(const bf16x8*)(wps_c + pc_nt * 8192 + kt * 1024 + lnoff);
            py = __builtin_amdgcn_mfma_f32_16x16x32_bf16(ah, wfr, py, 0, 0, 0);
        }
        if (pc_col < 20) {
            #pragma unroll
            for (int r = 0; r < 4; r++) {
                int row = pc_mt * 16 + lq * 4 + r;
                outp[((size_t)(b0 + row) * TT + (t - 1)) * DD + pc_col] = py[r];
                xbh[row * 32 + pc_col] = __float2bfloat16(py[r]);
            }
        }
    };

    // ---- pipeline prologue: panels 0,1 -> bufs 0,1; ensure panel 0 deposited ----
    int bufC = 0;                    // buffer of next panel to consume
    stagePanelIdx(0, 0);
    stagePanelIdx(1, 1);
    wait_vm4();                      // panel 0 (oldest 4) complete
    barrier_nd();

    #pragma unroll 1
    for (int t = 0; t < TT; t++) {
        // ======== phase A: gates0 = bias0 + h0 @ W0h^T + x @ W0x^T ========
        #pragma unroll
        for (int q = 0; q < 8; q++) {
            f32x4 v = {bs0[q], bs0[q], bs0[q], bs0[q]};
            acc[q][0] = v; acc[q][1] = v;
        }
        #pragma unroll
        for (int s = 0; s < 16; s++) {
            int bufS = bufC + 2; if (bufS >= 3) bufS -= 3;
            stagePanelIdx(s + 2, bufS);
            if (s == 0 && t > 0 && wv < 4) phaseC(t);
            consumeH(bufC, s >> 1, s & 1, h0c);
            wait_vm4();
            barrier_nd();
            bufC = (bufC == 2) ? 0 : bufC + 1;
        }
        #pragma unroll
        for (int s = 16; s < 18; s++) {
            int bufS = bufC + 2; if (bufS >= 3) bufS -= 3;
            stagePanelIdx(s + 2, bufS);
            consumeX(bufC, s - 16);
            wait_vm4();
            barrier_nd();
            bufC = (bufC == 2) ? 0 : bufC + 1;
        }
        // ---- EW-A: c0,h0 update (in place) ----
        #pragma unroll
        for (int mt = 0; mt < 2; mt++)
            #pragma unroll
            for (int h = 0; h < 2; h++)
                #pragma unroll
                for (int r = 0; r < 4; r++) {
                    float iv = acc[0 + h][mt][r], fv = acc[2 + h][mt][r];
                    float gv = acc[4 + h][mt][r], ov = acc[6 + h][mt][r];
                    float cn = sigf(fv) * c0r[mt][h][r] + sigf(iv) * tanhfast(gv);
                    float hn = sigf(ov) * tanhfast(cn);
                    c0r[mt][h][r] = cn;
                    h0p[(mt * 16 + lq * 4 + r) * 264 + wv * 32 + h * 16 + l15] = __float2bfloat16(hn);
                }
        barrier_nd(); // h0_new visible

        // ======== phase B: gates1 = bias1 + h0_new @ W1x^T + h1 @ W1h^T ========
        #pragma unroll
        for (int q = 0; q < 8; q++) {
            f32x4 v = {bs1[q], bs1[q], bs1[q], bs1[q]};
            acc[q][0] = v; acc[q][1] = v;
        }
        #pragma unroll
        for (int j = 0; j < 32; j++) {
            int bufS = bufC + 2; if (bufS >= 3) bufS -= 3;
            stagePanelIdx(20 + j, bufS);     // wraps to next step's panels 0,1 at j=30,31
            if (j < 16) consumeH(bufC, j >> 1, j & 1, h0c);
            else        consumeH(bufC, (j - 16) >> 1, (j - 16) & 1, h1c);
            wait_vm4();
            barrier_nd();
            bufC = (bufC == 2) ? 0 : bufC + 1;
        }
        // ---- EW-B: c1,h1 update (in place) ----
        #pragma unroll
        for (int mt = 0; mt < 2; mt++)
            #pragma unroll
            for (int h = 0; h < 2; h++)
                #pragma unroll
                for (int r = 0; r < 4; r++) {
                    float iv = acc[0 + h][mt][r], fv = acc[2 + h][mt][r];
                    float gv = acc[4 + h][mt][r], ov = acc[6 + h][mt][r];
                    float cn = sigf(fv) * c1r[mt][h][r] + sigf(iv) * tanhfast(gv);
                    float hn = sigf(ov) * tanhfast(cn);
                    c1r[mt][h][r] = cn;
                    h1p[(mt * 16 + lq * 4 + r) * 264 + wv * 32 + h * 16 + l15] = __float2bfloat16(hn);
                }
        barrier_nd(); // h1_new visible
    }

    // final y(TT-1)
    if (wv < 4) phaseC(TT);
}

extern "C" void kernel_launch(void* const* d_in, const int* in_sizes, int n_in,
                              void* d_out, int out_size, void* d_ws, size_t ws_size,
                              hipStream_t stream) {
    const float* z      = (const float*)d_in[0];
    const float* w_lh   = (const float*)d_in[3];
    const float* b_lh   = (const float*)d_in[4];
    const float* w_lc   = (const float*)d_in[5];
    const float* b_lc   = (const float*)d_in[6];
    const float* w_ih0  = (const float*)d_in[7];
    const float* w_hh0  = (const float*)d_in[8];
    const float* b_ih0  = (const float*)d_in[9];
    const float* b_hh0  = (const float*)d_in[10];
    const float* w_ih1  = (const float*)d_in[11];
    const float* w_hh1  = (const float*)d_in[12];
    const float* b_ih1  = (const float*)d_in[13];
    const float* b_hh1  = (const float*)d_in[14];
    const float* w_proj = (const float*)d_in[15];
    const float* b_proj = (const float*)d_in[16];
    char* ws = (char*)d_ws;
    float* out = (float*)d_out;

    prep_kernel<<<3240, 256, 0, stream>>>(w_ih0, w_hh0, w_ih1, w_hh1, w_proj,
                                          b_ih0, b_hh0, b_ih1, b_hh1, ws);
    decoder_kernel<<<NBLK, 512, 0, stream>>>(z, w_lh, b_lh, w_lc, b_lc, b_proj, ws, out);
}